// Round 4
// baseline (387.370 us; speedup 1.0000x reference)
//
#include <hip/hip_runtime.h>

// GRU: B=2048, T=1024, I=1, H=20, fused output projection.
// One wave per sequence (2048 waves = 2/SIMD). Packed-fp32 lane layout:
//   lane j   (0..19) : pk pair (r_j, n_j) dots; owns h_j.  r is LOCAL to n.
//   lane 32+j(0..19) : pk pair (z_j, j==0 ? y : 0) dots.
//   other lanes      : zero weights.
// Weights pre-scaled: r,z rows *log2e; n rows *2log2e (exp2-only activations);
// y row unscaled on lane 32's hi half.
// h-broadcast: 20x v_readlane -> SGPR, duplicated to a 64-bit SGPR pair on the
// SALU pipe; v_pk_fma_f32 takes the pair as its one scalar operand.
// Only z crosses lanes (1 bpermute, issued early, consumed at the last FMA).

#define LOG2E 1.44269504088896340736f

typedef float f32x2 __attribute__((ext_vector_type(2)));

static __device__ __forceinline__ float fast_rcp(float x) {
    return __builtin_amdgcn_rcpf(x);
}
static __device__ __forceinline__ float exp2neg(float x) {   // 2^(-x)
    float r; asm("v_exp_f32 %0, -%1" : "=v"(r) : "v"(x)); return r;
}
static __device__ __forceinline__ float exp2pos(float x) {   // 2^(x)
    float r; asm("v_exp_f32 %0, %1" : "=v"(r) : "v"(x)); return r;
}
static __device__ __forceinline__ unsigned long long dup_sgpr(unsigned int u) {
    return (((unsigned long long)u) << 32) | (unsigned long long)u;
}
// acc += w * broadcast(h)   (h duplicated in an SGPR pair)
static __device__ __forceinline__ void pk_fma_acc(f32x2& acc, f32x2 w,
                                                  unsigned long long hp) {
    asm("v_pk_fma_f32 %0, %1, %2, %0" : "+v"(acc) : "v"(w), "s"(hp));
}
// d = w * broadcast(h)
static __device__ __forceinline__ f32x2 pk_mul(f32x2 w, unsigned long long hp) {
    f32x2 d; asm("v_pk_mul_f32 %0, %1, %2" : "=v"(d) : "v"(w), "s"(hp));
    return d;
}
// d = xf * broadcast(x) + cb
static __device__ __forceinline__ f32x2 pk_fma3(f32x2 xf, unsigned long long xp,
                                                f32x2 cb) {
    f32x2 d;
    asm("v_pk_fma_f32 %0, %1, %2, %3" : "=v"(d) : "v"(xf), "s"(xp), "v"(cb));
    return d;
}
static __device__ __forceinline__ f32x2 pk_add(f32x2 a, f32x2 b) {
    f32x2 d; asm("v_pk_add_f32 %0, %1, %2" : "=v"(d) : "v"(a), "v"(b));
    return d;
}
static __device__ __forceinline__ int rfl(float v) {   // readfirstlane (uniform)
    return __builtin_amdgcn_readfirstlane(__float_as_int(v));
}

__global__ __launch_bounds__(64) void gru_pk(
    const float* __restrict__ X,     // [B, T]
    const float* __restrict__ H0,    // [B, 20]
    const float* __restrict__ Wih,   // [60]
    const float* __restrict__ Whh,   // [60, 20]
    const float* __restrict__ Bih,   // [60]
    const float* __restrict__ Bhh,   // [60]
    const float* __restrict__ Wout,  // [20]
    const float* __restrict__ Bout,  // [1]
    float* __restrict__ Y,           // [B*T]
    float* __restrict__ Hlast)       // [B, 20]
{
    constexpr int T = 1024;
    constexpr int H = 20;
    const int b    = blockIdx.x;
    const int lane = threadIdx.x;

    __shared__ float lds[128];   // 0..63: y ring; 64..127: junk sink

    // ---- per-lane constants ----
    f32x2 w[H];
    f32x2 cb = {0.f, 0.f}, xf = {0.f, 0.f};
    float wihn2 = 0.f, bihn2 = 0.f;
    if (lane < 20) {                       // (r_j, n_j)
        #pragma unroll
        for (int k = 0; k < H; ++k)
            w[k] = f32x2{Whh[lane * H + k] * LOG2E,
                         Whh[(40 + lane) * H + k] * (2.f * LOG2E)};
        cb    = f32x2{(Bih[lane] + Bhh[lane]) * LOG2E,
                      Bhh[40 + lane] * (2.f * LOG2E)};
        xf    = f32x2{Wih[lane] * LOG2E, 0.f};
        wihn2 = Wih[40 + lane] * (2.f * LOG2E);
        bihn2 = Bih[40 + lane] * (2.f * LOG2E);
    } else if (lane >= 32 && lane < 52) {  // (z_j, y-row on j==0)
        const int j = lane - 32;
        #pragma unroll
        for (int k = 0; k < H; ++k)
            w[k] = f32x2{Whh[(20 + j) * H + k] * LOG2E,
                         (j == 0) ? Wout[k] : 0.f};
        cb = f32x2{(Bih[20 + j] + Bhh[20 + j]) * LOG2E,
                   (j == 0) ? Bout[0] : 0.f};
        xf = f32x2{Wih[20 + j] * LOG2E, 0.f};
    } else {
        #pragma unroll
        for (int k = 0; k < H; ++k) w[k] = f32x2{0.f, 0.f};
    }

    const bool isy = (lane == 32);
    const int  ztr = (lane < 32) ? (lane + 32) : lane;   // z transport src

    float hcur = H0[b * H + ((lane < 20) ? lane : 0)];

    const float4* X4 = (const float4*)(X + (size_t)b * T);
    float4 xq = X4[0];

    for (int q = 0; q < T / 4; ++q) {
        const int qn = (q < T / 4 - 1) ? (q + 1) : (T / 4 - 1);
        float4 xn = X4[qn];
        #pragma unroll
        for (int u = 0; u < 4; ++u) {
            const int   i  = 4 * q + u;
            const float xv = (u == 0) ? xq.x : (u == 1) ? xq.y
                           : (u == 2) ? xq.z : xq.w;

            // flush 64 y-values every 64 steps (i == 65, 129, ..., 961)
            if (u == 1 && (q & 15) == 0 && q > 0) {
                Y[(size_t)b * T + (4 * q - 64) + lane] = lds[lane];
            }

            // uniform x -> scalar, duplicated pair
            const unsigned int      xu = (unsigned int)rfl(xv);
            const unsigned long long xp = dup_sgpr(xu);

            // broadcast h (lanes 0..19) into SGPR pairs
            unsigned long long hp[H];
            #pragma unroll
            for (int k = 0; k < H; ++k)
                hp[k] = dup_sgpr(
                    (unsigned int)__builtin_amdgcn_readlane(
                        __float_as_int(hcur), k));

            // packed dots, 4 chains of 5
            f32x2 a0 = pk_fma3(xf, xp, cb);
            f32x2 a1 = pk_mul(w[1], hp[1]);
            f32x2 a2 = pk_mul(w[2], hp[2]);
            f32x2 a3 = pk_mul(w[3], hp[3]);
            pk_fma_acc(a0, w[0], hp[0]);
            #pragma unroll
            for (int k = 4; k < H; k += 4) {
                pk_fma_acc(a0, w[k],     hp[k]);
                pk_fma_acc(a1, w[k + 1], hp[k + 1]);
                pk_fma_acc(a2, w[k + 2], hp[k + 2]);
                pk_fma_acc(a3, w[k + 3], hp[k + 3]);
            }
            const f32x2 acc = pk_add(pk_add(a0, a1), pk_add(a2, a3));

            // sigmoid on lo half: r (lanes 0..19), z (lanes 32..51)
            const float s = fast_rcp(1.f + exp2neg(acc.x));
            // z transport (issued now, consumed only at the final fma)
            const float zj = __shfl(s, ztr, 64);

            // n = tanh(gi + r*acc_n): all pre-scaled by 2*log2e; r is LOCAL
            const float gi   = fmaf(xv, wihn2, bihn2);
            const float npre = fmaf(s, acc.y, gi);
            const float nval = fmaf(fast_rcp(1.f + exp2pos(npre)), -2.f, 1.f);
            hcur = fmaf(zj, hcur - nval, nval);

            // y ring: lane 32's acc.y == y_{i-1}
            const int waddr = isy ? ((i + 63) & 63) : (64 + lane);
            lds[waddr] = acc.y;
        }
        xq = xn;
    }

    // tail: y_{T-1} = W_out . h_T + b_out (only lane 32's hi half matters)
    {
        unsigned long long hp[H];
        #pragma unroll
        for (int k = 0; k < H; ++k)
            hp[k] = dup_sgpr(
                (unsigned int)__builtin_amdgcn_readlane(
                    __float_as_int(hcur), k));
        f32x2 a0 = cb;
        f32x2 a1 = pk_mul(w[1], hp[1]);
        f32x2 a2 = pk_mul(w[2], hp[2]);
        f32x2 a3 = pk_mul(w[3], hp[3]);
        pk_fma_acc(a0, w[0], hp[0]);
        #pragma unroll
        for (int k = 4; k < H; k += 4) {
            pk_fma_acc(a0, w[k],     hp[k]);
            pk_fma_acc(a1, w[k + 1], hp[k + 1]);
            pk_fma_acc(a2, w[k + 2], hp[k + 2]);
            pk_fma_acc(a3, w[k + 3], hp[k + 3]);
        }
        const f32x2 acc = pk_add(pk_add(a0, a1), pk_add(a2, a3));
        lds[isy ? 63 : (64 + lane)] = acc.y;
        Y[(size_t)b * T + (T - 64) + lane] = lds[lane];
    }

    if (lane < 20) Hlast[b * H + lane] = hcur;
}

extern "C" void kernel_launch(void* const* d_in, const int* in_sizes, int n_in,
                              void* d_out, int out_size, void* d_ws, size_t ws_size,
                              hipStream_t stream) {
    const float* X    = (const float*)d_in[0];
    const float* H0   = (const float*)d_in[1];
    const float* Wih  = (const float*)d_in[2];
    const float* Whh  = (const float*)d_in[3];
    const float* Bih  = (const float*)d_in[4];
    const float* Bhh  = (const float*)d_in[5];
    const float* Wout = (const float*)d_in[6];
    const float* Bout = (const float*)d_in[7];

    constexpr int B = 2048, T = 1024, H = 20;
    float* Y     = (float*)d_out;            // [1, B*T, 1] flattened
    float* Hlast = Y + (size_t)B * T;        // [1, B, H]

    gru_pk<<<dim3(B), dim3(64), 0, stream>>>(X, H0, Wih, Whh, Bih, Bhh,
                                             Wout, Bout, Y, Hlast);
}

// Round 5
// 359.365 us; speedup vs baseline: 1.0779x; 1.0779x over previous
//
#include <hip/hip_runtime.h>

// GRU: B=2048, T=1024, I=1, H=20, fused output projection.
// One wave per sequence (2048 waves = 2/SIMD). Lane layout:
//   lane j    (0..19) : pk pair (r_j, n_j) dots; owns h_j. r LOCAL to n.
//   lane 32+j (0..19) : pk pair (z_j, j==0 ? y-row : 0).
//   others            : zero weights (junk, bounded).
// h-broadcast: owner lanes ds_write_b64 {h_j,h_j}; all lanes read 20
// uniform-address ds_read_b64 -> zero VALU cost, latency hidden by the
// sibling wave on the SIMD. Only z crosses lanes (1 bpermute, consumed
// at the final fma, overlapped with tanh).
// Weights pre-scaled: r,z *log2e; n *2log2e -> raw v_exp (2^x) only.

#define LOG2E 1.44269504088896340736f

typedef float f32x2 __attribute__((ext_vector_type(2)));

static __device__ __forceinline__ float fast_rcp(float x) {
    return __builtin_amdgcn_rcpf(x);
}
static __device__ __forceinline__ float exp2neg(float x) {   // 2^(-x)
    float r; asm("v_exp_f32 %0, -%1" : "=v"(r) : "v"(x)); return r;
}
static __device__ __forceinline__ float exp2pos(float x) {   // 2^(x)
    float r; asm("v_exp_f32 %0, %1" : "=v"(r) : "v"(x)); return r;
}

__global__ __launch_bounds__(64) void gru_lds(
    const float* __restrict__ X,     // [B, T]
    const float* __restrict__ H0,    // [B, 20]
    const float* __restrict__ Wih,   // [60]
    const float* __restrict__ Whh,   // [60, 20]
    const float* __restrict__ Bih,   // [60]
    const float* __restrict__ Bhh,   // [60]
    const float* __restrict__ Wout,  // [20]
    const float* __restrict__ Bout,  // [1]
    float* __restrict__ Y,           // [B*T]
    float* __restrict__ Hlast)       // [B, 20]
{
    constexpr int T = 1024;
    constexpr int H = 20;
    const int b    = blockIdx.x;
    const int lane = threadIdx.x;

    // [0..39]: h duplicated pairs {h_k,h_k}; [64..127]: y ring;
    // [128..255]: junk (even idx = h-store junk, odd idx = ring junk).
    __shared__ __align__(16) float lds[256];

    // ---- per-lane constants ----
    f32x2 w[H];
    f32x2 cb = {0.f, 0.f};
    float wihlo = 0.f, wihn2 = 0.f, bihn2 = 0.f;
    if (lane < 20) {                       // (r_j, n_j)
        #pragma unroll
        for (int k = 0; k < H; ++k)
            w[k] = f32x2{Whh[lane * H + k] * LOG2E,
                         Whh[(40 + lane) * H + k] * (2.f * LOG2E)};
        cb    = f32x2{(Bih[lane] + Bhh[lane]) * LOG2E,
                      Bhh[40 + lane] * (2.f * LOG2E)};
        wihlo = Wih[lane] * LOG2E;
        wihn2 = Wih[40 + lane] * (2.f * LOG2E);
        bihn2 = Bih[40 + lane] * (2.f * LOG2E);
    } else if (lane >= 32 && lane < 52) {  // (z_j, y-row on j==0)
        const int j = lane - 32;
        #pragma unroll
        for (int k = 0; k < H; ++k)
            w[k] = f32x2{Whh[(20 + j) * H + k] * LOG2E,
                         (j == 0) ? Wout[k] : 0.f};
        cb    = f32x2{(Bih[20 + j] + Bhh[20 + j]) * LOG2E,
                      (j == 0) ? Bout[0] : 0.f};
        wihlo = Wih[20 + j] * LOG2E;
    } else {
        #pragma unroll
        for (int k = 0; k < H; ++k) w[k] = f32x2{0.f, 0.f};
    }

    const bool isy    = (lane == 32);
    const int  zsrc   = (lane < 20) ? (lane + 32) : lane;  // bpermute src
    const int  hstore = (lane < 20) ? (2 * lane) : (128 + 2 * lane);
    const int  rjunk  = 129 + 2 * lane;                    // odd junk slots

    float hcur = H0[b * H + ((lane < 20) ? lane : 0)];
    *(f32x2*)&lds[hstore] = f32x2{hcur, hcur};             // initial h pairs

    const float4* X4 = (const float4*)(X + (size_t)b * T);
    float4 xq = X4[0];

    for (int q = 0; q < T / 4; ++q) {
        const int qn = (q < T / 4 - 1) ? (q + 1) : (T / 4 - 1);
        float4 xn = X4[qn];
        #pragma unroll
        for (int u = 0; u < 4; ++u) {
            const int   i  = 4 * q + u;
            const float xv = (u == 0) ? xq.x : (u == 1) ? xq.y
                           : (u == 2) ? xq.z : xq.w;

            // flush 64 y-values every 64 steps (i == 65, 129, ..., 961)
            if (u == 1 && (q & 15) == 0 && q > 0) {
                Y[(size_t)b * T + (4 * q - 64) + lane] = lds[64 + lane];
            }

            // broadcast h: 20 uniform-address b64 reads (dup pairs)
            const f32x2 h0  = *(const f32x2*)&lds[0];
            const f32x2 h1  = *(const f32x2*)&lds[2];
            const f32x2 h2  = *(const f32x2*)&lds[4];
            const f32x2 h3  = *(const f32x2*)&lds[6];
            const f32x2 h4  = *(const f32x2*)&lds[8];
            const f32x2 h5  = *(const f32x2*)&lds[10];
            const f32x2 h6  = *(const f32x2*)&lds[12];
            const f32x2 h7  = *(const f32x2*)&lds[14];
            const f32x2 h8  = *(const f32x2*)&lds[16];
            const f32x2 h9  = *(const f32x2*)&lds[18];
            const f32x2 h10 = *(const f32x2*)&lds[20];
            const f32x2 h11 = *(const f32x2*)&lds[22];
            const f32x2 h12 = *(const f32x2*)&lds[24];
            const f32x2 h13 = *(const f32x2*)&lds[26];
            const f32x2 h14 = *(const f32x2*)&lds[28];
            const f32x2 h15 = *(const f32x2*)&lds[30];
            const f32x2 h16 = *(const f32x2*)&lds[32];
            const f32x2 h17 = *(const f32x2*)&lds[34];
            const f32x2 h18 = *(const f32x2*)&lds[36];
            const f32x2 h19 = *(const f32x2*)&lds[38];

            // packed dot, 4 independent chains (compiler -> v_pk_fma_f32)
            f32x2 a0 = __builtin_elementwise_fma(w[0], h0, cb);
            f32x2 a1 = w[1] * h1;
            f32x2 a2 = w[2] * h2;
            f32x2 a3 = w[3] * h3;
            a0 = __builtin_elementwise_fma(w[4],  h4,  a0);
            a1 = __builtin_elementwise_fma(w[5],  h5,  a1);
            a2 = __builtin_elementwise_fma(w[6],  h6,  a2);
            a3 = __builtin_elementwise_fma(w[7],  h7,  a3);
            a0 = __builtin_elementwise_fma(w[8],  h8,  a0);
            a1 = __builtin_elementwise_fma(w[9],  h9,  a1);
            a2 = __builtin_elementwise_fma(w[10], h10, a2);
            a3 = __builtin_elementwise_fma(w[11], h11, a3);
            a0 = __builtin_elementwise_fma(w[12], h12, a0);
            a1 = __builtin_elementwise_fma(w[13], h13, a1);
            a2 = __builtin_elementwise_fma(w[14], h14, a2);
            a3 = __builtin_elementwise_fma(w[15], h15, a3);
            a0 = __builtin_elementwise_fma(w[16], h16, a0);
            a1 = __builtin_elementwise_fma(w[17], h17, a1);
            a2 = __builtin_elementwise_fma(w[18], h18, a2);
            a3 = __builtin_elementwise_fma(w[19], h19, a3);
            const f32x2 acc = (a0 + a1) + (a2 + a3);

            // lo-half pre-activation: r (lanes 0..19) / z (lanes 32..51)
            const float accx = fmaf(xv, wihlo, acc.x);
            const float s    = fast_rcp(1.f + exp2neg(accx));

            // z transport (issued early, consumed at the final fma)
            const float zj = __shfl(s, zsrc, 64);

            // n = tanh(gi + r*acc_n): pre-scaled by 2*log2e; r is LOCAL
            const float gi   = fmaf(xv, wihn2, bihn2);
            const float npre = fmaf(s, acc.y, gi);
            const float nval = fmaf(fast_rcp(1.f + exp2pos(npre)), -2.f, 1.f);
            const float hnew = fmaf(zj, hcur - nval, nval);
            hcur = hnew;                 // only lanes 0..19 ever read back

            // store h pair for next step's broadcast (+ junk lanes)
            *(f32x2*)&lds[hstore] = f32x2{hnew, hnew};

            // y ring: lane 32's acc.y == y_{i-1}
            const int ridx = isy ? (64 + ((i + 63) & 63)) : rjunk;
            lds[ridx] = acc.y;
        }
        xq = xn;
    }

    // tail: y_{T-1} = W_out . h_T + b_out (lane 32's hi half)
    {
        const f32x2* hp = (const f32x2*)lds;
        f32x2 a0 = __builtin_elementwise_fma(w[0], hp[0], cb);
        f32x2 a1 = w[1] * hp[1];
        f32x2 a2 = w[2] * hp[2];
        f32x2 a3 = w[3] * hp[3];
        #pragma unroll
        for (int k = 4; k < H; k += 4) {
            a0 = __builtin_elementwise_fma(w[k],     hp[k],     a0);
            a1 = __builtin_elementwise_fma(w[k + 1], hp[k + 1], a1);
            a2 = __builtin_elementwise_fma(w[k + 2], hp[k + 2], a2);
            a3 = __builtin_elementwise_fma(w[k + 3], hp[k + 3], a3);
        }
        const f32x2 acc = (a0 + a1) + (a2 + a3);
        lds[isy ? 127 : rjunk] = acc.y;          // slot 63 of the ring
        Y[(size_t)b * T + (T - 64) + lane] = lds[64 + lane];
    }

    if (lane < 20) Hlast[b * H + lane] = hcur;
}

extern "C" void kernel_launch(void* const* d_in, const int* in_sizes, int n_in,
                              void* d_out, int out_size, void* d_ws, size_t ws_size,
                              hipStream_t stream) {
    const float* X    = (const float*)d_in[0];
    const float* H0   = (const float*)d_in[1];
    const float* Wih  = (const float*)d_in[2];
    const float* Whh  = (const float*)d_in[3];
    const float* Bih  = (const float*)d_in[4];
    const float* Bhh  = (const float*)d_in[5];
    const float* Wout = (const float*)d_in[6];
    const float* Bout = (const float*)d_in[7];

    constexpr int B = 2048, T = 1024, H = 20;
    float* Y     = (float*)d_out;            // [1, B*T, 1] flattened
    float* Hlast = Y + (size_t)B * T;        // [1, B, H]

    gru_lds<<<dim3(B), dim3(64), 0, stream>>>(X, H0, Wih, Whh, Bih, Bhh,
                                              Wout, Bout, Y, Hlast);
}

// Round 7
// 307.822 us; speedup vs baseline: 1.2584x; 1.1674x over previous
//
#include <hip/hip_runtime.h>

// GRU: B=2048, T=1024, I=1, H=20, fused output projection.
// One wave per sequence (2048 waves = 2/SIMD). R2 structure with the
// r-transport moved OFF the LDS pipe onto VALU via v_permlane32_swap_b32.
// Lane layout:
//   lanes  0..19 : r rows   (row = lane;      weights pre-scaled by log2e)
//   lanes 20..31 : z rows 0..11  (row = lane; log2e)
//   lanes 32..51 : n rows   (row = lane + 8;  2*log2e); lane 32+j owns h[j]
//   lanes 52..59 : z rows 12..19 (row = lane - 20; log2e)
//   lane  60     : W_out row -> y from the same shared dot
//   lanes 61..63 : zero weights (idle)
// r transport: lane j -> lane 32+j via ONE v_permlane32_swap_b32 (VALU,
// ~6 cy) -- this was the ~80 cy ds_bpermute on the critical chain in R2.
// z transport: ds_bpermute, issued right after sigmoid, consumed only at
// the final fma (after tanh) -> latency hidden.
// h-broadcast: 20x v_readlane from lanes 32..51.
// y: lane 60 ds_writes a 64-slot LDS ring; coalesced flush every 64 steps.

#define LOG2E 1.44269504088896340736f

static __device__ __forceinline__ float fast_rcp(float x) {
    return __builtin_amdgcn_rcpf(x);
}
static __device__ __forceinline__ float exp2neg(float x) {   // 2^(-x)
    float r; asm("v_exp_f32 %0, -%1" : "=v"(r) : "v"(x)); return r;
}
static __device__ __forceinline__ float exp2pos(float x) {   // 2^(x)
    float r; asm("v_exp_f32 %0, %1" : "=v"(r) : "v"(x)); return r;
}
static __device__ __forceinline__ float lane_bcast(float v, int srclane) {
    return __int_as_float(__builtin_amdgcn_readlane(__float_as_int(v), srclane));
}
// lanes 32+j receive v from lane j (VALU cross-lane, low latency).
// v_permlane32_swap_b32 d, s: swaps d[0..31] with s[32..63]; we return s,
// whose lanes 32..63 now hold v from lanes 0..31. (Self-aliasing is fine.)
static __device__ __forceinline__ float swap_up(float v) {
    float d = v, s = v;
    asm("v_permlane32_swap_b32 %0, %1" : "+v"(d), "+v"(s));
    return s;
}

__global__ __launch_bounds__(64) void gru_pl(
    const float* __restrict__ X,     // [B, T]
    const float* __restrict__ H0,    // [B, 20]
    const float* __restrict__ Wih,   // [60]
    const float* __restrict__ Whh,   // [60, 20]
    const float* __restrict__ Bih,   // [60]
    const float* __restrict__ Bhh,   // [60]
    const float* __restrict__ Wout,  // [20]
    const float* __restrict__ Bout,  // [1]
    float* __restrict__ Y,           // [B*T]
    float* __restrict__ Hlast)       // [B, 20]
{
    constexpr int T = 1024;
    constexpr int H = 20;
    const int b    = blockIdx.x;
    const int lane = threadIdx.x;

    __shared__ float lds[128];   // 0..63: y ring; 64..127: junk sink

    const bool is_n  = (lane >= 32) && (lane < 52);
    const bool is_rz = (lane < 32) || (lane >= 52 && lane < 60);
    // gate-row index per lane (see layout above)
    const int row = (lane < 32) ? lane
                  : (lane < 52) ? (lane + 8)
                  : (lane < 60) ? (lane - 20) : 0;

    // ---- per-lane constants ----
    float w[H];
    float wih_full = 0.f, bihv = 0.f, cbias = 0.f, wih_rz = 0.f;
    if (is_rz) {                          // r or z row: scale log2e
        #pragma unroll
        for (int k = 0; k < H; ++k) w[k] = Whh[row * H + k] * LOG2E;
        cbias  = (Bih[row] + Bhh[row]) * LOG2E;
        wih_rz = Wih[row] * LOG2E;
    } else if (is_n) {                    // n row: scale 2*log2e
        #pragma unroll
        for (int k = 0; k < H; ++k) w[k] = Whh[row * H + k] * (2.f * LOG2E);
        cbias    = Bhh[row] * (2.f * LOG2E);
        wih_full = Wih[row] * (2.f * LOG2E);
        bihv     = Bih[row] * (2.f * LOG2E);
    } else if (lane == 60) {              // y row: unscaled
        #pragma unroll
        for (int k = 0; k < H; ++k) w[k] = Wout[k];
        cbias = Bout[0];
    } else {
        #pragma unroll
        for (int k = 0; k < H; ++k) w[k] = 0.f;
    }

    const int jn = lane - 32;             // n index (valid on n-lanes)
    // z transport src for n-lane 32+j: z_j at lane 20+j (j<12) else 40+j
    const int sz = is_n ? ((lane < 44) ? (lane - 12) : (lane + 8)) : lane;

    float hcur = H0[b * H + (is_n ? jn : 0)];

    const float4* X4 = (const float4*)(X + (size_t)b * T);
    float4 xq = X4[0];

    for (int q = 0; q < T / 4; ++q) {
        const int qn = (q < T / 4 - 1) ? (q + 1) : (T / 4 - 1);
        float4 xn = X4[qn];
        #pragma unroll
        for (int u = 0; u < 4; ++u) {
            const int   i  = 4 * q + u;
            const float xv = (u == 0) ? xq.x : (u == 1) ? xq.y
                           : (u == 2) ? xq.z : xq.w;

            // flush 64 y-values every 64 steps (i == 65, 129, ..., 961)
            if (u == 1 && (q & 15) == 0 && q > 0) {
                Y[(size_t)b * T + (4 * q - 64) + lane] = lds[lane];
            }

            // broadcast h (owners: lanes 32..51)
            float hs[H];
            #pragma unroll
            for (int k = 0; k < H; ++k) hs[k] = lane_bcast(hcur, 32 + k);

            // shared pre-activation dot: 4 ILP chains of 5
            float a0 = fmaf(xv, wih_rz, cbias);
            float gi = fmaf(xv, wih_full, bihv);
            float a1 = hs[1] * w[1];
            float a2 = hs[2] * w[2];
            float a3 = hs[3] * w[3];
            a0 = fmaf(hs[0], w[0], a0);
            #pragma unroll
            for (int k = 4; k < H; k += 4) {
                a0 = fmaf(hs[k],     w[k],     a0);
                a1 = fmaf(hs[k + 1], w[k + 1], a1);
                a2 = fmaf(hs[k + 2], w[k + 2], a2);
                a3 = fmaf(hs[k + 3], w[k + 3], a3);
            }
            const float acc = (a0 + a1) + (a2 + a3);

            // sigmoid (valid on r/z lanes; harmless junk elsewhere)
            const float s = fast_rcp(1.f + exp2neg(acc));

            // r: lane j -> lane 32+j via permlane (VALU, on-chain but fast)
            const float rj = swap_up(s);
            // z: ds_bpermute, consumed only at the last fma (hidden)
            const float zj = __shfl(s, sz, 64);

            // n = tanh(gi + r*acc_n): pre-scaled by 2*log2e
            const float npre = fmaf(rj, acc, gi);
            const float nval = fmaf(fast_rcp(1.f + exp2pos(npre)), -2.f, 1.f);
            hcur = fmaf(zj, hcur - nval, nval);

            // y ring: lane 60's acc == y_{i-1}
            lds[(lane == 60) ? ((i + 63) & 63) : (64 + lane)] = acc;
        }
        xq = xn;
    }

    // tail: y_{T-1} = W_out . h_T + b_out
    {
        float hs[H];
        #pragma unroll
        for (int k = 0; k < H; ++k) hs[k] = lane_bcast(hcur, 32 + k);
        float a0 = cbias;
        float a1 = hs[1] * w[1];
        float a2 = hs[2] * w[2];
        float a3 = hs[3] * w[3];
        a0 = fmaf(hs[0], w[0], a0);
        #pragma unroll
        for (int k = 4; k < H; k += 4) {
            a0 = fmaf(hs[k],     w[k],     a0);
            a1 = fmaf(hs[k + 1], w[k + 1], a1);
            a2 = fmaf(hs[k + 2], w[k + 2], a2);
            a3 = fmaf(hs[k + 3], w[k + 3], a3);
        }
        const float acc = (a0 + a1) + (a2 + a3);
        lds[(lane == 60) ? 63 : (64 + lane)] = acc;
        Y[(size_t)b * T + (T - 64) + lane] = lds[lane];
    }

    if (is_n) Hlast[b * H + jn] = hcur;
}

extern "C" void kernel_launch(void* const* d_in, const int* in_sizes, int n_in,
                              void* d_out, int out_size, void* d_ws, size_t ws_size,
                              hipStream_t stream) {
    const float* X    = (const float*)d_in[0];
    const float* H0   = (const float*)d_in[1];
    const float* Wih  = (const float*)d_in[2];
    const float* Whh  = (const float*)d_in[3];
    const float* Bih  = (const float*)d_in[4];
    const float* Bhh  = (const float*)d_in[5];
    const float* Wout = (const float*)d_in[6];
    const float* Bout = (const float*)d_in[7];

    constexpr int B = 2048, T = 1024, H = 20;
    float* Y     = (float*)d_out;            // [1, B*T, 1] flattened
    float* Hlast = Y + (size_t)B * T;        // [1, B, H]

    gru_pl<<<dim3(B), dim3(64), 0, stream>>>(X, H0, Wih, Whh, Bih, Bhh,
                                             Wout, Bout, Y, Hlast);
}